// Round 8
// baseline (326.308 us; speedup 1.0000x reference)
//
#include <hip/hip_runtime.h>
#include <hip/hip_bf16.h>
#include <stdint.h>

#define B_DIM 8192
#define K_DIM 2048
#define N_DIM 2048
#define NSEG 4
#define NT (K_DIM / 64)   // 32 K-tiles of BK=64

typedef short bf16x8 __attribute__((ext_vector_type(8)));   // 8 bf16 (4 VGPRs)
typedef float f32x4 __attribute__((ext_vector_type(4)));
typedef unsigned short ushort8v __attribute__((ext_vector_type(8)));

typedef const __attribute__((address_space(1))) void* gas_ptr;
typedef __attribute__((address_space(3))) void* lds_ptr;

__device__ __forceinline__ unsigned short f2bf(float f) {
  uint32_t u = __float_as_uint(f);
  u += 0x7FFFu + ((u >> 16) & 1u);   // round-to-nearest-even
  return (unsigned short)(u >> 16);
}

// ---------------- W: f32 -> bf16 conversion, 8 elems/thread ----------------
__global__ __launch_bounds__(256)
void convert_kernel(const float* __restrict__ in, unsigned short* __restrict__ out, int n8) {
  int i = blockIdx.x * blockDim.x + threadIdx.x;
  const int stride = gridDim.x * blockDim.x;
  for (; i < n8; i += stride) {
    const float4* p = (const float4*)(in + (size_t)i * 8);
    float4 v0 = p[0];
    float4 v1 = p[1];
    ushort8v r;
    r[0] = f2bf(v0.x); r[1] = f2bf(v0.y); r[2] = f2bf(v0.z); r[3] = f2bf(v0.w);
    r[4] = f2bf(v1.x); r[5] = f2bf(v1.y); r[6] = f2bf(v1.z); r[7] = f2bf(v1.w);
    *(ushort8v*)(out + (size_t)i * 8) = r;
  }
}

// ------ fused: x f32 -> bf16 convert + gates = sigmoid(x @ Wg^T + bg) ------
__global__ __launch_bounds__(256)
void xconv_gates_kernel(const float* __restrict__ x, const float* __restrict__ Wg,
                        const float* __restrict__ bg,
                        unsigned short* __restrict__ xb, float* __restrict__ gates) {
  const int b = blockIdx.x;
  const int tid = threadIdx.x;
  const size_t base = (size_t)b * K_DIM + tid * 8;
  const float4 v0 = *(const float4*)(x + base);
  const float4 v1 = *(const float4*)(x + base + 4);
  ushort8v r;
  r[0] = f2bf(v0.x); r[1] = f2bf(v0.y); r[2] = f2bf(v0.z); r[3] = f2bf(v0.w);
  r[4] = f2bf(v1.x); r[5] = f2bf(v1.y); r[6] = f2bf(v1.z); r[7] = f2bf(v1.w);
  *(ushort8v*)(xb + base) = r;

  float a[4];
#pragma unroll
  for (int s = 0; s < 4; ++s) {
    const float4 w0 = *(const float4*)(Wg + (size_t)s * K_DIM + tid * 8);
    const float4 w1 = *(const float4*)(Wg + (size_t)s * K_DIM + tid * 8 + 4);
    a[s] = v0.x * w0.x + v0.y * w0.y + v0.z * w0.z + v0.w * w0.w
         + v1.x * w1.x + v1.y * w1.y + v1.z * w1.z + v1.w * w1.w;
  }
#pragma unroll
  for (int off = 1; off < 64; off <<= 1) {
#pragma unroll
    for (int s = 0; s < 4; ++s) a[s] += __shfl_xor(a[s], off);
  }
  __shared__ float red[4][4];
  const int wv = tid >> 6;
  if ((tid & 63) == 0) {
#pragma unroll
    for (int s = 0; s < 4; ++s) red[wv][s] = a[s];
  }
  __syncthreads();
  if (tid < 4) {
    float v = red[0][tid] + red[1][tid] + red[2][tid] + red[3][tid] + bg[tid];
    gates[(size_t)b * 4 + tid] = 1.f / (1.f + __expf(-v));
  }
}

// ---- fused 4-segment GEMM: m201-literal 4-phase barrier-pair schedule ------
// Geometry (verified R2/R5): block 256 rows x 64 d x 4 segs, 8 waves 2Mx4N,
// per-wave 128 rows x 16 d x 4 segs, acc[4][8] f32x4 = 128 VGPR.
// Per K-tile: 4 phases; phase = {ds_reads (12 or 4 b128) | 1 half-tile stage |
// [lgkmcnt(8) if 12 reads] | barrier | lgkmcnt(0) | setprio1 | 16 MFMA |
// setprio0 | barrier}. A-quad (4 mf x 2 kk) held across 2 phases; B seg-pair
// re-read each phase (m201's bounded-register re-read pattern). The
// barrier-pair per phase keeps the 2 waves/SIMD in role-split so ds_reads of
// one interleave with MFMAs of the other (the m218b mechanism).
// LDS 160K: A dbuf 2x32K, B tri-buf 3x32K. Stages: ph0/1 -> A(t+1) halves,
// ph2/3 -> B(t+2) halves into dead 3rd buffer. Tile-end vmcnt(4), never 0
// mid-loop; vmcnt(0) only at t==NT-2.
__global__ __launch_bounds__(512, 2)
void seg_gemm_kernel(const unsigned short* __restrict__ Xb,
                     const unsigned short* __restrict__ Wb,
                     const float* __restrict__ b_seg,
                     const float* __restrict__ thr,
                     const float* __restrict__ gates,
                     float* __restrict__ out) {
  extern __shared__ __align__(128) char smem[];   // 163840 bytes

  const int tid = threadIdx.x;
  const int lane = tid & 63;
  const int wid = tid >> 6;
  const int wm = wid >> 2;        // 0..1 (m half)
  const int wn = wid & 3;         // 0..3 (d quarter)

  // bijective XCD swizzle: 1024 blocks, 8 XCDs, 128 per XCD
  const int id = blockIdx.x;
  const int swz = (id & 7) * 128 + (id >> 3);
  const int m0 = (swz >> 5) * 256;
  const int n0 = (swz & 31) * 64;

  // ---- staging constants (verified zero-conflict, R2/R5) ----
  const int row_st = ((tid >> 7) << 4) + ((tid >> 2) & 15);          // + j*64
  const int kb_st  = (((tid >> 6) & 1) << 6) + ((((tid & 3) << 4)) ^ (((tid >> 5) & 1) << 5));
  const int ke_st  = kb_st >> 1;
  const int ldsd   = tid * 16;

  // ---- read constants (verified zero-conflict, R2/R5) ----
  const int l15 = lane & 15;
  const int kg  = lane >> 4;       // 0..3
  const int aRd = l15 * 64 + ((kg * 16) ^ ((l15 & 8) << 2));
  const int wnB = wn * 2048;

  f32x4 acc[NSEG][8];
#pragma unroll
  for (int s = 0; s < NSEG; ++s)
#pragma unroll
    for (int f = 0; f < 8; ++f) acc[s][f] = (f32x4){0.f, 0.f, 0.f, 0.f};

#define STAGE_A(t_, h_) do { int buf_ = (t_) & 1;                                   \
    const unsigned short* s0_ = Xb + (size_t)(m0 + (h_) * 128 + row_st) * K_DIM + (t_) * 64 + ke_st; \
    __builtin_amdgcn_global_load_lds((gas_ptr)s0_, (lds_ptr)(smem + buf_ * 32768 + (h_) * 16384 + ldsd), 16, 0, 0); \
    const unsigned short* s1_ = Xb + (size_t)(m0 + (h_) * 128 + row_st + 64) * K_DIM + (t_) * 64 + ke_st; \
    __builtin_amdgcn_global_load_lds((gas_ptr)s1_, (lds_ptr)(smem + buf_ * 32768 + (h_) * 16384 + ldsd + 8192), 16, 0, 0); \
  } while (0)

#define STAGE_B(t_, h_, bb_) do {                                                   \
    int e0_ = (h_) * 128 + row_st;                                                  \
    const unsigned short* s0_ = Wb + (size_t)(e0_ >> 6) * (N_DIM * K_DIM) + (size_t)(n0 + (e0_ & 63)) * K_DIM + (t_) * 64 + ke_st; \
    __builtin_amdgcn_global_load_lds((gas_ptr)s0_, (lds_ptr)(smem + 65536 + (bb_) * 32768 + (h_) * 16384 + ldsd), 16, 0, 0); \
    int e1_ = e0_ + 64;                                                             \
    const unsigned short* s1_ = Wb + (size_t)(e1_ >> 6) * (N_DIM * K_DIM) + (size_t)(n0 + (e1_ & 63)) * K_DIM + (t_) * 64 + ke_st; \
    __builtin_amdgcn_global_load_lds((gas_ptr)s1_, (lds_ptr)(smem + 65536 + (bb_) * 32768 + (h_) * 16384 + ldsd + 8192), 16, 0, 0); \
  } while (0)

#define MFMA16(a_, b_, c_) __builtin_amdgcn_mfma_f32_16x16x32_bf16(a_, b_, c_, 0, 0, 0)
#define LD8(p_) (*(const bf16x8*)(p_))

  // 16-MFMA cluster: A-quad aq[4][2] x B-pair bp[2][2] -> segs (sa,sb), mf base c0
#define MM16(sa_, sb_, c0_) do {                                                    \
    __builtin_amdgcn_s_setprio(1);                                                  \
    _Pragma("unroll")                                                               \
    for (int kk = 0; kk < 2; ++kk) {                                                \
      _Pragma("unroll")                                                             \
      for (int f = 0; f < 4; ++f) {                                                 \
        acc[sa_][(c0_) + f] = MFMA16(aq[f][kk], bp[0][kk], acc[sa_][(c0_) + f]);    \
        acc[sb_][(c0_) + f] = MFMA16(aq[f][kk], bp[1][kk], acc[sb_][(c0_) + f]);    \
      }                                                                             \
    }                                                                               \
    __builtin_amdgcn_s_setprio(0);                                                  \
  } while (0)

#define RD_AQ(base_) do {                                                           \
    _Pragma("unroll")                                                               \
    for (int f = 0; f < 4; ++f) {                                                   \
      aq[f][0] = LD8(Ab + ((base_) + f) * 2048 + aRd);                              \
      aq[f][1] = LD8(Ab + ((base_) + f) * 2048 + 1024 + aRd);                       \
    }                                                                               \
  } while (0)

#define RD_BP(s0_) do {                                                             \
    bp[0][0] = LD8(Bb + (s0_) * 8192 + wnB + aRd);                                  \
    bp[0][1] = LD8(Bb + (s0_) * 8192 + wnB + 1024 + aRd);                           \
    bp[1][0] = LD8(Bb + ((s0_) + 1) * 8192 + wnB + aRd);                            \
    bp[1][1] = LD8(Bb + ((s0_) + 1) * 8192 + wnB + 1024 + aRd);                     \
  } while (0)

  // ---- prologue: A(0), B(0)->buf0, B(1)->buf1; keep B(1) in flight ----
  STAGE_A(0, 0); STAGE_A(0, 1);
  STAGE_B(0, 0, 0); STAGE_B(0, 1, 0);
  STAGE_B(1, 0, 1); STAGE_B(1, 1, 1);
  asm volatile("s_waitcnt vmcnt(4)" ::: "memory");   // A(0),B(0) landed
  __builtin_amdgcn_s_barrier();

  int bc = 0, bs = 2;   // current / stage-target B buffer (mod 3)
  for (int t = 0; t < NT; ++t) {
    const char* Ab = smem + (t & 1) * 32768 + wm * 16384;
    const char* Bb = smem + 65536 + bc * 32768;
    bf16x8 aq[4][2];
    bf16x8 bp[2][2];

    // ---- phase 0: Aq(mf0-3) + B s01 (12 reads); stage A(t+1).h0 ----
    RD_AQ(0); RD_BP(0);
    if (t + 1 < NT) STAGE_A(t + 1, 0);
    asm volatile("s_waitcnt lgkmcnt(8)" ::: "memory");
    __builtin_amdgcn_s_barrier();
    asm volatile("s_waitcnt lgkmcnt(0)" ::: "memory");
    MM16(0, 1, 0);
    __builtin_amdgcn_s_barrier();

    // ---- phase 1: B s23 (4 reads, Aq held); stage A(t+1).h1 ----
    RD_BP(2);
    if (t + 1 < NT) STAGE_A(t + 1, 1);
    __builtin_amdgcn_s_barrier();
    asm volatile("s_waitcnt lgkmcnt(0)" ::: "memory");
    MM16(2, 3, 0);
    __builtin_amdgcn_s_barrier();

    // ---- phase 2: Aq(mf4-7) + B s01 re-read (12); stage B(t+2).h0 ----
    RD_AQ(4); RD_BP(0);
    if (t + 2 < NT) STAGE_B(t + 2, 0, bs);
    asm volatile("s_waitcnt lgkmcnt(8)" ::: "memory");
    __builtin_amdgcn_s_barrier();
    asm volatile("s_waitcnt lgkmcnt(0)" ::: "memory");
    MM16(0, 1, 4);
    __builtin_amdgcn_s_barrier();

    // ---- phase 3: B s23 re-read (4); stage B(t+2).h1; vmcnt tail ----
    RD_BP(2);
    if (t + 2 < NT) STAGE_B(t + 2, 1, bs);
    __builtin_amdgcn_s_barrier();
    asm volatile("s_waitcnt lgkmcnt(0)" ::: "memory");
    MM16(2, 3, 4);
    if (t < NT - 2)      { asm volatile("s_waitcnt vmcnt(4)" ::: "memory"); }
    else if (t == NT - 2){ asm volatile("s_waitcnt vmcnt(0)" ::: "memory"); }
    __builtin_amdgcn_s_barrier();

    bc = (bc == 2) ? 0 : bc + 1;
    bs = (bs == 2) ? 0 : bs + 1;
  }
  asm volatile("s_waitcnt lgkmcnt(0) vmcnt(0)" ::: "memory");

  // ---------------- epilogue ----------------
  // C/D layout: col = lane&15 (d), row = (lane>>4)*4 + reg (batch)
  const int d = n0 + wn * 16 + l15;
  float bsv[NSEG], thv[NSEG];
#pragma unroll
  for (int s = 0; s < NSEG; ++s) {
    bsv[s] = b_seg[s * N_DIM + d];
    thv[s] = thr[s * N_DIM + d];
  }
#pragma unroll
  for (int f = 0; f < 8; ++f) {
#pragma unroll
    for (int r = 0; r < 4; ++r) {
      const int brow = m0 + wm * 128 + f * 16 + kg * 4 + r;
      const float4 g = *(const float4*)(gates + (size_t)brow * 4);
      const float gv[NSEG] = {g.x, g.y, g.z, g.w};
      float sum = 0.f, prod = 1.f;
#pragma unroll
      for (int s = 0; s < NSEG; ++s) {
        const float seg = acc[s][f][r] + bsv[s];
        const float pl = 1.f / (1.f + __expf(-5.f * (seg - thv[s])));
        const float st = seg * pl * gv[s];
        sum += st;
        prod *= st;
      }
      const float gm = sqrtf(sqrtf(fabsf(prod)));   // |prod|^(1/4)
      out[(size_t)brow * N_DIM + d] = sum + 0.1f * (prod < 0.f ? -gm : gm);
    }
  }
#undef STAGE_A
#undef STAGE_B
#undef MFMA16
#undef LD8
#undef MM16
#undef RD_AQ
#undef RD_BP
}

extern "C" void kernel_launch(void* const* d_in, const int* in_sizes, int n_in,
                              void* d_out, int out_size, void* d_ws, size_t ws_size,
                              hipStream_t stream) {
  const float* x      = (const float*)d_in[0];
  const float* W_seg  = (const float*)d_in[1];
  const float* b_seg  = (const float*)d_in[2];
  const float* thr    = (const float*)d_in[3];
  const float* W_gate = (const float*)d_in[4];
  const float* b_gate = (const float*)d_in[5];
  float* out = (float*)d_out;

  // workspace layout: x_bf16 (32MB) | W_bf16 (32MB) | gates (128KB)
  unsigned short* xb = (unsigned short*)d_ws;
  unsigned short* wb = xb + (size_t)B_DIM * K_DIM;
  float* gates = (float*)(wb + (size_t)NSEG * N_DIM * K_DIM);

  xconv_gates_kernel<<<B_DIM, 256, 0, stream>>>(x, W_gate, b_gate, xb, gates);
  convert_kernel<<<2048, 256, 0, stream>>>(W_seg, wb, NSEG * N_DIM * K_DIM / 8);

  hipFuncSetAttribute((const void*)seg_gemm_kernel,
                      hipFuncAttributeMaxDynamicSharedMemorySize, 163840);
  seg_gemm_kernel<<<1024, 512, 163840, stream>>>(xb, wb, b_seg, thr, gates, out);
}

// Round 9
// 309.524 us; speedup vs baseline: 1.0542x; 1.0542x over previous
//
#include <hip/hip_runtime.h>
#include <hip/hip_bf16.h>
#include <stdint.h>

#define B_DIM 8192
#define K_DIM 2048
#define N_DIM 2048
#define NSEG 4
#define NT (K_DIM / 64)   // 32 K-tiles of BK=64

typedef short bf16x8 __attribute__((ext_vector_type(8)));   // 8 bf16 (4 VGPRs)
typedef float f32x4 __attribute__((ext_vector_type(4)));
typedef unsigned short ushort8v __attribute__((ext_vector_type(8)));

typedef const __attribute__((address_space(1))) void* gas_ptr;
typedef __attribute__((address_space(3))) void* lds_ptr;

__device__ __forceinline__ unsigned short f2bf(float f) {
  uint32_t u = __float_as_uint(f);
  u += 0x7FFFu + ((u >> 16) & 1u);   // round-to-nearest-even
  return (unsigned short)(u >> 16);
}

// ---------------- W: f32 -> bf16 conversion, 8 elems/thread ----------------
__global__ __launch_bounds__(256)
void convert_kernel(const float* __restrict__ in, unsigned short* __restrict__ out, int n8) {
  int i = blockIdx.x * blockDim.x + threadIdx.x;
  const int stride = gridDim.x * blockDim.x;
  for (; i < n8; i += stride) {
    const float4* p = (const float4*)(in + (size_t)i * 8);
    float4 v0 = p[0];
    float4 v1 = p[1];
    ushort8v r;
    r[0] = f2bf(v0.x); r[1] = f2bf(v0.y); r[2] = f2bf(v0.z); r[3] = f2bf(v0.w);
    r[4] = f2bf(v1.x); r[5] = f2bf(v1.y); r[6] = f2bf(v1.z); r[7] = f2bf(v1.w);
    *(ushort8v*)(out + (size_t)i * 8) = r;
  }
}

// ------ fused: x f32 -> bf16 convert + gates = sigmoid(x @ Wg^T + bg) ------
__global__ __launch_bounds__(256)
void xconv_gates_kernel(const float* __restrict__ x, const float* __restrict__ Wg,
                        const float* __restrict__ bg,
                        unsigned short* __restrict__ xb, float* __restrict__ gates) {
  const int b = blockIdx.x;
  const int tid = threadIdx.x;
  const size_t base = (size_t)b * K_DIM + tid * 8;
  const float4 v0 = *(const float4*)(x + base);
  const float4 v1 = *(const float4*)(x + base + 4);
  ushort8v r;
  r[0] = f2bf(v0.x); r[1] = f2bf(v0.y); r[2] = f2bf(v0.z); r[3] = f2bf(v0.w);
  r[4] = f2bf(v1.x); r[5] = f2bf(v1.y); r[6] = f2bf(v1.z); r[7] = f2bf(v1.w);
  *(ushort8v*)(xb + base) = r;

  float a[4];
#pragma unroll
  for (int s = 0; s < 4; ++s) {
    const float4 w0 = *(const float4*)(Wg + (size_t)s * K_DIM + tid * 8);
    const float4 w1 = *(const float4*)(Wg + (size_t)s * K_DIM + tid * 8 + 4);
    a[s] = v0.x * w0.x + v0.y * w0.y + v0.z * w0.z + v0.w * w0.w
         + v1.x * w1.x + v1.y * w1.y + v1.z * w1.z + v1.w * w1.w;
  }
#pragma unroll
  for (int off = 1; off < 64; off <<= 1) {
#pragma unroll
    for (int s = 0; s < 4; ++s) a[s] += __shfl_xor(a[s], off);
  }
  __shared__ float red[4][4];
  const int wv = tid >> 6;
  if ((tid & 63) == 0) {
#pragma unroll
    for (int s = 0; s < 4; ++s) red[wv][s] = a[s];
  }
  __syncthreads();
  if (tid < 4) {
    float v = red[0][tid] + red[1][tid] + red[2][tid] + red[3][tid] + bg[tid];
    gates[(size_t)b * 4 + tid] = 1.f / (1.f + __expf(-v));
  }
}

// --- fused 4-segment GEMM: anti-phased waves + 2-phase-cover counted lgkm ---
// Geometry (verified): block 256 rows x 64 d x 4 segs, 8 waves 2Mx4N,
// per-wave 128 rows x 16 d x 4 segs, acc[4][8] f32x4.
// Mechanism 1 (anti-phase): SIMD s hosts waves wid=s (wm=0) and wid=s+4
// (wm=1). wm=1 runs the A-pair phases rotated (2,3,0,1) so the two waves on
// one SIMD alternate {ds_read burst} vs {MFMA cluster} -> LDS unit and matrix
// pipe overlap instead of sum-serializing (the 45% wall of R2/R5/R7/R8).
// Mechanism 2 (2-phase cover): start burst 16 ds_reads, then reads issued 2
// MFMA-phases ahead with exact counted lgkmcnt(8/4/0); 24 reads/tile minimal,
// 3-slot A register rotation keeps VGPR ~225.
// LDS 160K: A dbuf 2x32K, B tri-buf 3x32K; stages after waits; tile-end
// vmcnt(4) (0 only at NT-2); 1 barrier/tile.
__global__ __launch_bounds__(512, 2)
void seg_gemm_kernel(const unsigned short* __restrict__ Xb,
                     const unsigned short* __restrict__ Wb,
                     const float* __restrict__ b_seg,
                     const float* __restrict__ thr,
                     const float* __restrict__ gates,
                     float* __restrict__ out) {
  extern __shared__ __align__(128) char smem[];   // 163840 bytes

  const int tid = threadIdx.x;
  const int lane = tid & 63;
  const int wid = tid >> 6;
  const int wm = wid >> 2;        // 0..1 (m half)  [SIMD partner differs in wm]
  const int wn = wid & 3;         // 0..3 (d quarter)

  // bijective XCD swizzle: 1024 blocks, 8 XCDs, 128 per XCD
  const int id = blockIdx.x;
  const int swz = (id & 7) * 128 + (id >> 3);
  const int m0 = (swz >> 5) * 256;
  const int n0 = (swz & 31) * 64;

  // ---- staging constants (verified zero-conflict) ----
  const int row_st = ((tid >> 7) << 4) + ((tid >> 2) & 15);          // + j*64
  const int kb_st  = (((tid >> 6) & 1) << 6) + ((((tid & 3) << 4)) ^ (((tid >> 5) & 1) << 5));
  const int ke_st  = kb_st >> 1;
  const int ldsd   = tid * 16;

  // ---- read constants (verified zero-conflict) ----
  const int l15 = lane & 15;
  const int kg  = lane >> 4;       // 0..3
  const int aRd = l15 * 64 + ((kg * 16) ^ ((l15 & 8) << 2));
  const int wnB = wn * 2048;

  f32x4 acc[NSEG][8];
#pragma unroll
  for (int s = 0; s < NSEG; ++s)
#pragma unroll
    for (int f = 0; f < 8; ++f) acc[s][f] = (f32x4){0.f, 0.f, 0.f, 0.f};

#define STAGE_A(t_, h_) do { int buf_ = (t_) & 1;                                   \
    const unsigned short* s0_ = Xb + (size_t)(m0 + (h_) * 128 + row_st) * K_DIM + (t_) * 64 + ke_st; \
    __builtin_amdgcn_global_load_lds((gas_ptr)s0_, (lds_ptr)(smem + buf_ * 32768 + (h_) * 16384 + ldsd), 16, 0, 0); \
    const unsigned short* s1_ = Xb + (size_t)(m0 + (h_) * 128 + row_st + 64) * K_DIM + (t_) * 64 + ke_st; \
    __builtin_amdgcn_global_load_lds((gas_ptr)s1_, (lds_ptr)(smem + buf_ * 32768 + (h_) * 16384 + ldsd + 8192), 16, 0, 0); \
  } while (0)

#define STAGE_B(t_, h_, bb_) do {                                                   \
    int e0_ = (h_) * 128 + row_st;                                                  \
    const unsigned short* s0_ = Wb + (size_t)(e0_ >> 6) * (N_DIM * K_DIM) + (size_t)(n0 + (e0_ & 63)) * K_DIM + (t_) * 64 + ke_st; \
    __builtin_amdgcn_global_load_lds((gas_ptr)s0_, (lds_ptr)(smem + 65536 + (bb_) * 32768 + (h_) * 16384 + ldsd), 16, 0, 0); \
    int e1_ = e0_ + 64;                                                             \
    const unsigned short* s1_ = Wb + (size_t)(e1_ >> 6) * (N_DIM * K_DIM) + (size_t)(n0 + (e1_ & 63)) * K_DIM + (t_) * 64 + ke_st; \
    __builtin_amdgcn_global_load_lds((gas_ptr)s1_, (lds_ptr)(smem + 65536 + (bb_) * 32768 + (h_) * 16384 + ldsd + 8192), 16, 0, 0); \
  } while (0)

#define MFMA16(a_, b_, c_) __builtin_amdgcn_mfma_f32_16x16x32_bf16(a_, b_, c_, 0, 0, 0)
#define LD8(p_) (*(const bf16x8*)(p_))
#define WAITL(n_) asm volatile("s_waitcnt lgkmcnt(" #n_ ")" ::: "memory")

  // read A m-pair q into slot sl
#define RD_AP(sl_, q_) do {                                                         \
    ap##sl_[0][0] = LD8(Ab + (2 * (q_)    ) * 2048 + aRd);                          \
    ap##sl_[0][1] = LD8(Ab + (2 * (q_)    ) * 2048 + 1024 + aRd);                   \
    ap##sl_[1][0] = LD8(Ab + (2 * (q_) + 1) * 2048 + aRd);                          \
    ap##sl_[1][1] = LD8(Ab + (2 * (q_) + 1) * 2048 + 1024 + aRd);                   \
  } while (0)

#define RD_B(p_) do {                                                               \
    b[2 * (p_)][0]     = LD8(Bb + (2 * (p_)) * 8192 + wnB + aRd);                   \
    b[2 * (p_)][1]     = LD8(Bb + (2 * (p_)) * 8192 + wnB + 1024 + aRd);            \
    b[2 * (p_) + 1][0] = LD8(Bb + (2 * (p_) + 1) * 8192 + wnB + aRd);               \
    b[2 * (p_) + 1][1] = LD8(Bb + (2 * (p_) + 1) * 8192 + wnB + 1024 + aRd);        \
  } while (0)

  // 8 MFMA: A-pair slot sl x seg-pair (sa,sb), acc f-base f0
#define MM8(sl_, sa_, sb_, f0_) do {                                                \
    __builtin_amdgcn_s_setprio(1);                                                  \
    _Pragma("unroll")                                                               \
    for (int kk = 0; kk < 2; ++kk) {                                                \
      acc[sa_][(f0_)]     = MFMA16(ap##sl_[0][kk], b[sa_][kk], acc[sa_][(f0_)]);    \
      acc[sa_][(f0_) + 1] = MFMA16(ap##sl_[1][kk], b[sa_][kk], acc[sa_][(f0_) + 1]);\
      acc[sb_][(f0_)]     = MFMA16(ap##sl_[0][kk], b[sb_][kk], acc[sb_][(f0_)]);    \
      acc[sb_][(f0_) + 1] = MFMA16(ap##sl_[1][kk], b[sb_][kk], acc[sb_][(f0_) + 1]);\
    }                                                                               \
    __builtin_amdgcn_s_setprio(0);                                                  \
  } while (0)

  // full K-tile body with A-pair order (qA,qB,qC,qD); 24 ds_reads, counted lgkm
#define TILEBODY(qA_, qB_, qC_, qD_) do {                                           \
    RD_AP(0, qA_); RD_B(0); RD_B(1); RD_AP(1, qB_);   /* 16 reads out */            \
    WAITL(8);                       /* apA + b01 done */                            \
    if (t + 1 < NT) STAGE_A(t + 1, 0);                                              \
    MM8(0, 0, 1, 2 * (qA_));                                                        \
    RD_AP(2, qC_);                  /* out: b23, apB, apC = 12 */                   \
    WAITL(8);                       /* b23 done */                                  \
    MM8(0, 2, 3, 2 * (qA_));                                                        \
    RD_AP(0, qD_);                  /* slot0 reuse; out: apB, apC, apD = 12 */      \
    WAITL(8);                       /* apB done */                                  \
    if (t + 1 < NT) STAGE_A(t + 1, 1);                                              \
    MM8(1, 0, 1, 2 * (qB_));                                                        \
    MM8(1, 2, 3, 2 * (qB_));                                                        \
    WAITL(4);                       /* apC done */                                  \
    if (t + 2 < NT) STAGE_B(t + 2, 0, bs);                                          \
    MM8(2, 0, 1, 2 * (qC_));                                                        \
    if (t + 2 < NT) STAGE_B(t + 2, 1, bs);                                          \
    MM8(2, 2, 3, 2 * (qC_));                                                        \
    WAITL(0);                       /* apD done */                                  \
    MM8(0, 0, 1, 2 * (qD_));                                                        \
    MM8(0, 2, 3, 2 * (qD_));                                                        \
    if (t < NT - 2)      { asm volatile("s_waitcnt vmcnt(4)" ::: "memory"); }       \
    else if (t == NT - 2){ asm volatile("s_waitcnt vmcnt(0)" ::: "memory"); }       \
    __builtin_amdgcn_s_barrier();                                                   \
    bc = (bc == 2) ? 0 : bc + 1;                                                    \
    bs = (bs == 2) ? 0 : bs + 1;                                                    \
  } while (0)

  // ---- prologue: A(0), B(0)->buf0, B(1)->buf1; keep B(1) in flight ----
  STAGE_A(0, 0); STAGE_A(0, 1);
  STAGE_B(0, 0, 0); STAGE_B(0, 1, 0);
  STAGE_B(1, 0, 1); STAGE_B(1, 1, 1);
  asm volatile("s_waitcnt vmcnt(4)" ::: "memory");   // A(0),B(0) landed
  __builtin_amdgcn_s_barrier();

  int bc = 0, bs = 2;   // current / stage-target B buffer (mod 3)
  bf16x8 ap0[2][2], ap1[2][2], ap2[2][2];
  bf16x8 b[NSEG][2];

  if (wm == 0) {
    for (int t = 0; t < NT; ++t) {
      const char* Ab = smem + (t & 1) * 32768;             // wm=0 half
      const char* Bb = smem + 65536 + bc * 32768;
      TILEBODY(0, 1, 2, 3);
    }
  } else {
    for (int t = 0; t < NT; ++t) {
      const char* Ab = smem + (t & 1) * 32768 + 16384;     // wm=1 half
      const char* Bb = smem + 65536 + bc * 32768;
      TILEBODY(2, 3, 0, 1);                                // anti-phased order
    }
  }
  asm volatile("s_waitcnt lgkmcnt(0) vmcnt(0)" ::: "memory");

  // ---------------- epilogue ----------------
  // C/D layout: col = lane&15 (d), row = (lane>>4)*4 + reg (batch)
  const int d = n0 + wn * 16 + l15;
  float bsv[NSEG], thv[NSEG];
#pragma unroll
  for (int s = 0; s < NSEG; ++s) {
    bsv[s] = b_seg[s * N_DIM + d];
    thv[s] = thr[s * N_DIM + d];
  }
#pragma unroll
  for (int f = 0; f < 8; ++f) {
#pragma unroll
    for (int r = 0; r < 4; ++r) {
      const int brow = m0 + wm * 128 + f * 16 + kg * 4 + r;
      const float4 g = *(const float4*)(gates + (size_t)brow * 4);
      const float gv[NSEG] = {g.x, g.y, g.z, g.w};
      float sum = 0.f, prod = 1.f;
#pragma unroll
      for (int s = 0; s < NSEG; ++s) {
        const float seg = acc[s][f][r] + bsv[s];
        const float pl = 1.f / (1.f + __expf(-5.f * (seg - thv[s])));
        const float st = seg * pl * gv[s];
        sum += st;
        prod *= st;
      }
      const float gm = sqrtf(sqrtf(fabsf(prod)));   // |prod|^(1/4)
      out[(size_t)brow * N_DIM + d] = sum + 0.1f * (prod < 0.f ? -gm : gm);
    }
  }
#undef STAGE_A
#undef STAGE_B
#undef MFMA16
#undef LD8
#undef WAITL
#undef RD_AP
#undef RD_B
#undef MM8
#undef TILEBODY
}

extern "C" void kernel_launch(void* const* d_in, const int* in_sizes, int n_in,
                              void* d_out, int out_size, void* d_ws, size_t ws_size,
                              hipStream_t stream) {
  const float* x      = (const float*)d_in[0];
  const float* W_seg  = (const float*)d_in[1];
  const float* b_seg  = (const float*)d_in[2];
  const float* thr    = (const float*)d_in[3];
  const float* W_gate = (const float*)d_in[4];
  const float* b_gate = (const float*)d_in[5];
  float* out = (float*)d_out;

  // workspace layout: x_bf16 (32MB) | W_bf16 (32MB) | gates (128KB)
  unsigned short* xb = (unsigned short*)d_ws;
  unsigned short* wb = xb + (size_t)B_DIM * K_DIM;
  float* gates = (float*)(wb + (size_t)NSEG * N_DIM * K_DIM);

  xconv_gates_kernel<<<B_DIM, 256, 0, stream>>>(x, W_gate, b_gate, xb, gates);
  convert_kernel<<<2048, 256, 0, stream>>>(W_seg, wb, NSEG * N_DIM * K_DIM / 8);

  hipFuncSetAttribute((const void*)seg_gemm_kernel,
                      hipFuncAttributeMaxDynamicSharedMemorySize, 163840);
  seg_gemm_kernel<<<1024, 512, 163840, stream>>>(xb, wb, b_seg, thr, gates, out);
}

// Round 10
// 228.156 us; speedup vs baseline: 1.4302x; 1.3566x over previous
//
#include <hip/hip_runtime.h>
#include <stdint.h>

#define B_DIM 8192
#define K_DIM 2048
#define N_DIM 2048
#define NSEG 4
#define NT (K_DIM / 64)   // 32 K-tiles of BK=64

typedef int v4i __attribute__((ext_vector_type(4)));

typedef const __attribute__((address_space(1))) void* gas_ptr;
typedef __attribute__((address_space(3))) void* lds_ptr;

// ---- fused: x row quantize (per-row int8) + gates = sigmoid(x@Wg^T+bg) ----
__global__ __launch_bounds__(256)
void xquant_gates_kernel(const float* __restrict__ x, const float* __restrict__ Wg,
                         const float* __restrict__ bg, signed char* __restrict__ xq,
                         float* __restrict__ sx, float* __restrict__ gates) {
  const int b = blockIdx.x;
  const int tid = threadIdx.x;
  const size_t base = (size_t)b * K_DIM + tid * 8;
  const float4 v0 = *(const float4*)(x + base);
  const float4 v1 = *(const float4*)(x + base + 4);

  float a[4];
#pragma unroll
  for (int s = 0; s < 4; ++s) {
    const float4 w0 = *(const float4*)(Wg + (size_t)s * K_DIM + tid * 8);
    const float4 w1 = *(const float4*)(Wg + (size_t)s * K_DIM + tid * 8 + 4);
    a[s] = v0.x * w0.x + v0.y * w0.y + v0.z * w0.z + v0.w * w0.w
         + v1.x * w1.x + v1.y * w1.y + v1.z * w1.z + v1.w * w1.w;
  }
  float m = fmaxf(fmaxf(fmaxf(fabsf(v0.x), fabsf(v0.y)), fmaxf(fabsf(v0.z), fabsf(v0.w))),
                  fmaxf(fmaxf(fabsf(v1.x), fabsf(v1.y)), fmaxf(fabsf(v1.z), fabsf(v1.w))));
#pragma unroll
  for (int off = 1; off < 64; off <<= 1) {
    m = fmaxf(m, __shfl_xor(m, off));
#pragma unroll
    for (int s = 0; s < 4; ++s) a[s] += __shfl_xor(a[s], off);
  }
  __shared__ float redg[4][4];
  __shared__ float rmx[4];
  const int wv = tid >> 6;
  if ((tid & 63) == 0) {
    rmx[wv] = m;
#pragma unroll
    for (int s = 0; s < 4; ++s) redg[wv][s] = a[s];
  }
  __syncthreads();
  const float rm = fmaxf(fmaxf(rmx[0], rmx[1]), fmaxf(rmx[2], rmx[3]));
  const float inv = 127.0f / fmaxf(rm, 1e-30f);
  const int q0 = __float2int_rn(v0.x * inv), q1 = __float2int_rn(v0.y * inv);
  const int q2 = __float2int_rn(v0.z * inv), q3 = __float2int_rn(v0.w * inv);
  const int q4 = __float2int_rn(v1.x * inv), q5 = __float2int_rn(v1.y * inv);
  const int q6 = __float2int_rn(v1.z * inv), q7 = __float2int_rn(v1.w * inv);
  const int lo = (q0 & 255) | ((q1 & 255) << 8) | ((q2 & 255) << 16) | ((q3 & 255) << 24);
  const int hi = (q4 & 255) | ((q5 & 255) << 8) | ((q6 & 255) << 16) | ((q7 & 255) << 24);
  ((int2*)xq)[(size_t)b * 256 + tid] = make_int2(lo, hi);
  if (tid == 0) sx[b] = rm * (1.0f / 127.0f);
  if (tid < 4) {
    float v = redg[0][tid] + redg[1][tid] + redg[2][tid] + redg[3][tid] + bg[tid];
    gates[(size_t)b * 4 + tid] = 1.f / (1.f + __expf(-v));
  }
}

// ---- W row quantize: one block per (seg,d) row of 2048 ----
__global__ __launch_bounds__(256)
void wquant_kernel(const float* __restrict__ W, signed char* __restrict__ wq,
                   float* __restrict__ sw) {
  const int row = blockIdx.x;           // s*N_DIM + d
  const int tid = threadIdx.x;
  const size_t base = (size_t)row * K_DIM + tid * 8;
  const float4 v0 = *(const float4*)(W + base);
  const float4 v1 = *(const float4*)(W + base + 4);
  float m = fmaxf(fmaxf(fmaxf(fabsf(v0.x), fabsf(v0.y)), fmaxf(fabsf(v0.z), fabsf(v0.w))),
                  fmaxf(fmaxf(fabsf(v1.x), fabsf(v1.y)), fmaxf(fabsf(v1.z), fabsf(v1.w))));
#pragma unroll
  for (int off = 1; off < 64; off <<= 1) m = fmaxf(m, __shfl_xor(m, off));
  __shared__ float rmx[4];
  if ((tid & 63) == 0) rmx[tid >> 6] = m;
  __syncthreads();
  const float rm = fmaxf(fmaxf(rmx[0], rmx[1]), fmaxf(rmx[2], rmx[3]));
  const float inv = 127.0f / fmaxf(rm, 1e-30f);
  const int q0 = __float2int_rn(v0.x * inv), q1 = __float2int_rn(v0.y * inv);
  const int q2 = __float2int_rn(v0.z * inv), q3 = __float2int_rn(v0.w * inv);
  const int q4 = __float2int_rn(v1.x * inv), q5 = __float2int_rn(v1.y * inv);
  const int q6 = __float2int_rn(v1.z * inv), q7 = __float2int_rn(v1.w * inv);
  const int lo = (q0 & 255) | ((q1 & 255) << 8) | ((q2 & 255) << 16) | ((q3 & 255) << 24);
  const int hi = (q4 & 255) | ((q5 & 255) << 8) | ((q6 & 255) << 16) | ((q7 & 255) << 24);
  ((int2*)wq)[(size_t)row * 256 + tid] = make_int2(lo, hi);
  if (tid == 0) sw[row] = rm * (1.0f / 127.0f);
}

// ------------- fused 4-segment GEMM, int8 MFMA 16x16x64 ---------------------
// Geometry (verified R2..R9): block 256 rows x 64 d x 4 segs, 8 waves 2Mx4N,
// per-wave 128 rows x 16 d x 4 segs; acc int32 v4i[4][8] = 128 VGPR.
// i8 halves both pipe terms: per tile per wave 12 ds_read_b128 (8 A + 4 B),
// 32 MFMA (K=64 per instr). LDS 80 KiB: A dbuf 2x16K, B tri-buf 3x16K.
// Swizzle: 16B chunk c of row r lives in slot c ^ ((r>>1)&3) (involution);
// reads are bijective 1KB/wave -> conflict-free (same class as verified bf16).
// Pipeline = R9's counted-lgkm: burst {b0..b3,a0,a1}, then 1-read-per-phase
// 2-phase cover, WAITL(3..0) never-0-early; stages A(t+1) early, B(t+2) at
// ph4/5 into dead 3rd buffer; tail vmcnt(2) (A/B(t+1) done, B(t+2) flying).
__global__ __launch_bounds__(512, 2)
void seg_gemm_kernel(const signed char* __restrict__ Xq,
                     const signed char* __restrict__ Wq,
                     const float* __restrict__ sx,
                     const float* __restrict__ sw,
                     const float* __restrict__ b_seg,
                     const float* __restrict__ thr,
                     const float* __restrict__ gates,
                     float* __restrict__ out) {
  extern __shared__ __align__(128) char smem[];   // 81920 bytes

  const int tid = threadIdx.x;
  const int lane = tid & 63;
  const int wid = tid >> 6;
  const int wm = wid >> 2;        // 0..1 (m half)
  const int wn = wid & 3;         // 0..3 (d quarter)

  // bijective XCD swizzle: 1024 blocks, 8 XCDs, 128 per XCD
  const int id = blockIdx.x;
  const int swz = (id & 7) * 128 + (id >> 3);
  const int m0 = (swz >> 5) * 256;
  const int n0 = (swz & 31) * 64;

  // ---- staging constants: dest L = tid*16 in an 8KB half; row = tid>>2,
  // slot = tid&3 holds global 16B-chunk kc = slot ^ ((row>>1)&3) ----
  const int row_st = tid >> 2;                       // 0..127
  const int kc    = (tid & 3) ^ ((tid >> 3) & 3);
  const int keOff = kc * 16;                         // byte==elem offset (i8)
  const int ldsd  = tid * 16;

  // ---- read constants: frag row = f*16+l15, chunk kg; slot = kg^((l15>>1)&3)
  const int l15 = lane & 15;
  const int kg  = lane >> 4;       // 0..3
  const int aSw = l15 * 64 + ((kg ^ ((l15 >> 1) & 3)) << 4);

  v4i acc[NSEG][8];
#pragma unroll
  for (int s = 0; s < NSEG; ++s)
#pragma unroll
    for (int f = 0; f < 8; ++f) acc[s][f] = (v4i){0, 0, 0, 0};

#define STAGE_A(t_, h_) do {                                                        \
    const signed char* s0_ = Xq + (size_t)(m0 + (h_) * 128 + row_st) * K_DIM + (t_) * 64 + keOff; \
    __builtin_amdgcn_global_load_lds((gas_ptr)s0_, (lds_ptr)(smem + ((t_) & 1) * 16384 + (h_) * 8192 + ldsd), 16, 0, 0); \
  } while (0)

#define STAGE_B(t_, h_, bb_) do {                                                   \
    const signed char* s0_ = Wq + ((size_t)((h_) * 2 + (tid >> 8)) * N_DIM + (n0 + ((tid >> 2) & 63))) * K_DIM + (t_) * 64 + keOff; \
    __builtin_amdgcn_global_load_lds((gas_ptr)s0_, (lds_ptr)(smem + 32768 + (bb_) * 16384 + (h_) * 8192 + ldsd), 16, 0, 0); \
  } while (0)

#define MFMAI(a_, b_, c_) __builtin_amdgcn_mfma_i32_16x16x64_i8(a_, b_, c_, 0, 0, 0)
#define LD16(p_) (*(const v4i*)(p_))
#define WAITL(n_) asm volatile("s_waitcnt lgkmcnt(" #n_ ")" ::: "memory")

#define MM4(f_) do {                                                                \
    __builtin_amdgcn_s_setprio(1);                                                  \
    acc[0][(f_)] = MFMAI(a[(f_)], bfr[0], acc[0][(f_)]);                            \
    acc[1][(f_)] = MFMAI(a[(f_)], bfr[1], acc[1][(f_)]);                            \
    acc[2][(f_)] = MFMAI(a[(f_)], bfr[2], acc[2][(f_)]);                            \
    acc[3][(f_)] = MFMAI(a[(f_)], bfr[3], acc[3][(f_)]);                            \
    __builtin_amdgcn_s_setprio(0);                                                  \
  } while (0)

  // ---- prologue: A(0) h0/h1, B(0) h0/h1, B(1) h0/h1; keep B(1) flying ----
  STAGE_A(0, 0); STAGE_A(0, 1);
  STAGE_B(0, 0, 0); STAGE_B(0, 1, 0);
  STAGE_B(1, 0, 1); STAGE_B(1, 1, 1);
  asm volatile("s_waitcnt vmcnt(2)" ::: "memory");   // A(0),B(0) landed
  __builtin_amdgcn_s_barrier();

  int bc = 0, bs = 2;   // current / stage-target B buffer (mod 3)
  for (int t = 0; t < NT; ++t) {
    const char* Ab = smem + (t & 1) * 16384 + wm * 8192;
    const char* Bb = smem + 32768 + bc * 16384;
    v4i bfr[NSEG];
    v4i a[8];

    // burst: B segs 0..3 + A frags 0,1 (6 lgkm out)
    bfr[0] = LD16(Bb + 0 * 4096 + wn * 1024 + aSw);
    bfr[1] = LD16(Bb + 1 * 4096 + wn * 1024 + aSw);
    bfr[2] = LD16(Bb + 2 * 4096 + wn * 1024 + aSw);
    bfr[3] = LD16(Bb + 3 * 4096 + wn * 1024 + aSw);
    a[0] = LD16(Ab + 0 * 1024 + aSw);
    a[1] = LD16(Ab + 1 * 1024 + aSw);
    if (t + 1 < NT) { STAGE_A(t + 1, 0); STAGE_A(t + 1, 1); }

    a[2] = LD16(Ab + 2 * 1024 + aSw);
    a[3] = LD16(Ab + 3 * 1024 + aSw);
    WAITL(3);  MM4(0);                               // b*,a0 done
    a[4] = LD16(Ab + 4 * 1024 + aSw);
    WAITL(3);  MM4(1);                               // a1 done
    a[5] = LD16(Ab + 5 * 1024 + aSw);
    WAITL(3);  MM4(2);                               // a2 done
    a[6] = LD16(Ab + 6 * 1024 + aSw);
    WAITL(3);  MM4(3);                               // a3 done
    a[7] = LD16(Ab + 7 * 1024 + aSw);
    WAITL(3);
    if (t + 2 < NT) STAGE_B(t + 2, 0, bs);
    MM4(4);                                          // a4 done
    WAITL(2);
    if (t + 2 < NT) STAGE_B(t + 2, 1, bs);
    MM4(5);                                          // a5 done
    WAITL(1);  MM4(6);                               // a6 done
    WAITL(0);  MM4(7);                               // a7 done

    if (t < NT - 2)      { asm volatile("s_waitcnt vmcnt(2)" ::: "memory"); }
    else if (t == NT - 2){ asm volatile("s_waitcnt vmcnt(0)" ::: "memory"); }
    __builtin_amdgcn_s_barrier();

    bc = (bc == 2) ? 0 : bc + 1;
    bs = (bs == 2) ? 0 : bs + 1;
  }
  asm volatile("s_waitcnt lgkmcnt(0) vmcnt(0)" ::: "memory");

  // ---------------- epilogue ----------------
  // C/D layout: col = lane&15 (d), row = (lane>>4)*4 + reg (dtype-independent)
  const int d = n0 + wn * 16 + l15;
  float bsv[NSEG], thv[NSEG], swv[NSEG];
#pragma unroll
  for (int s = 0; s < NSEG; ++s) {
    bsv[s] = b_seg[s * N_DIM + d];
    thv[s] = thr[s * N_DIM + d];
    swv[s] = sw[s * N_DIM + d];
  }
#pragma unroll
  for (int f = 0; f < 8; ++f) {
#pragma unroll
    for (int r = 0; r < 4; ++r) {
      const int brow = m0 + wm * 128 + f * 16 + kg * 4 + r;
      const float sxr = sx[brow];
      const float4 g = *(const float4*)(gates + (size_t)brow * 4);
      const float gv[NSEG] = {g.x, g.y, g.z, g.w};
      float sum = 0.f, prod = 1.f;
#pragma unroll
      for (int s = 0; s < NSEG; ++s) {
        const float seg = (float)acc[s][f][r] * (sxr * swv[s]) + bsv[s];
        const float pl = 1.f / (1.f + __expf(-5.f * (seg - thv[s])));
        const float st = seg * pl * gv[s];
        sum += st;
        prod *= st;
      }
      const float gm = sqrtf(sqrtf(fabsf(prod)));   // |prod|^(1/4)
      out[(size_t)brow * N_DIM + d] = sum + 0.1f * (prod < 0.f ? -gm : gm);
    }
  }
#undef STAGE_A
#undef STAGE_B
#undef MFMAI
#undef LD16
#undef WAITL
#undef MM4
}

extern "C" void kernel_launch(void* const* d_in, const int* in_sizes, int n_in,
                              void* d_out, int out_size, void* d_ws, size_t ws_size,
                              hipStream_t stream) {
  const float* x      = (const float*)d_in[0];
  const float* W_seg  = (const float*)d_in[1];
  const float* b_seg  = (const float*)d_in[2];
  const float* thr    = (const float*)d_in[3];
  const float* W_gate = (const float*)d_in[4];
  const float* b_gate = (const float*)d_in[5];
  float* out = (float*)d_out;

  // workspace: xq 16MB | wq 32MB | sx 32KB | sw 32KB | gates 128KB
  signed char* xq = (signed char*)d_ws;
  signed char* wq = xq + (size_t)B_DIM * K_DIM;
  float* sx = (float*)(wq + (size_t)NSEG * N_DIM * K_DIM);
  float* sw = sx + B_DIM;
  float* gates = sw + NSEG * N_DIM;

  xquant_gates_kernel<<<B_DIM, 256, 0, stream>>>(x, W_gate, b_gate, xq, sx, gates);
  wquant_kernel<<<NSEG * N_DIM, 256, 0, stream>>>(W_seg, wq, sw);

  hipFuncSetAttribute((const void*)seg_gemm_kernel,
                      hipFuncAttributeMaxDynamicSharedMemorySize, 81920);
  seg_gemm_kernel<<<1024, 512, 81920, stream>>>(xq, wq, sx, sw, b_seg, thr, gates, out);
}

// Round 11
// 227.857 us; speedup vs baseline: 1.4321x; 1.0013x over previous
//
#include <hip/hip_runtime.h>
#include <stdint.h>

#define B_DIM 8192
#define K_DIM 2048
#define N_DIM 2048
#define NSEG 4
#define NT (K_DIM / 64)   // 32 K-tiles of BK=64

typedef int v4i __attribute__((ext_vector_type(4)));

typedef const __attribute__((address_space(1))) void* gas_ptr;
typedef __attribute__((address_space(3))) void* lds_ptr;

// ---- fused: x row quantize (per-row int8) + gates = sigmoid(x@Wg^T+bg) ----
__global__ __launch_bounds__(256)
void xquant_gates_kernel(const float* __restrict__ x, const float* __restrict__ Wg,
                         const float* __restrict__ bg, signed char* __restrict__ xq,
                         float* __restrict__ sx, float* __restrict__ gates) {
  const int b = blockIdx.x;
  const int tid = threadIdx.x;
  const size_t base = (size_t)b * K_DIM + tid * 8;
  const float4 v0 = *(const float4*)(x + base);
  const float4 v1 = *(const float4*)(x + base + 4);

  float a[4];
#pragma unroll
  for (int s = 0; s < 4; ++s) {
    const float4 w0 = *(const float4*)(Wg + (size_t)s * K_DIM + tid * 8);
    const float4 w1 = *(const float4*)(Wg + (size_t)s * K_DIM + tid * 8 + 4);
    a[s] = v0.x * w0.x + v0.y * w0.y + v0.z * w0.z + v0.w * w0.w
         + v1.x * w1.x + v1.y * w1.y + v1.z * w1.z + v1.w * w1.w;
  }
  float m = fmaxf(fmaxf(fmaxf(fabsf(v0.x), fabsf(v0.y)), fmaxf(fabsf(v0.z), fabsf(v0.w))),
                  fmaxf(fmaxf(fabsf(v1.x), fabsf(v1.y)), fmaxf(fabsf(v1.z), fabsf(v1.w))));
#pragma unroll
  for (int off = 1; off < 64; off <<= 1) {
    m = fmaxf(m, __shfl_xor(m, off));
#pragma unroll
    for (int s = 0; s < 4; ++s) a[s] += __shfl_xor(a[s], off);
  }
  __shared__ float redg[4][4];
  __shared__ float rmx[4];
  const int wv = tid >> 6;
  if ((tid & 63) == 0) {
    rmx[wv] = m;
#pragma unroll
    for (int s = 0; s < 4; ++s) redg[wv][s] = a[s];
  }
  __syncthreads();
  const float rm = fmaxf(fmaxf(rmx[0], rmx[1]), fmaxf(rmx[2], rmx[3]));
  const float inv = 127.0f / fmaxf(rm, 1e-30f);
  const int q0 = __float2int_rn(v0.x * inv), q1 = __float2int_rn(v0.y * inv);
  const int q2 = __float2int_rn(v0.z * inv), q3 = __float2int_rn(v0.w * inv);
  const int q4 = __float2int_rn(v1.x * inv), q5 = __float2int_rn(v1.y * inv);
  const int q6 = __float2int_rn(v1.z * inv), q7 = __float2int_rn(v1.w * inv);
  const int lo = (q0 & 255) | ((q1 & 255) << 8) | ((q2 & 255) << 16) | ((q3 & 255) << 24);
  const int hi = (q4 & 255) | ((q5 & 255) << 8) | ((q6 & 255) << 16) | ((q7 & 255) << 24);
  ((int2*)xq)[(size_t)b * 256 + tid] = make_int2(lo, hi);
  if (tid == 0) sx[b] = rm * (1.0f / 127.0f);
  if (tid < 4) {
    float v = redg[0][tid] + redg[1][tid] + redg[2][tid] + redg[3][tid] + bg[tid];
    gates[(size_t)b * 4 + tid] = 1.f / (1.f + __expf(-v));
  }
}

// ---- W row quantize: one block per (seg,d) row of 2048 ----
__global__ __launch_bounds__(256)
void wquant_kernel(const float* __restrict__ W, signed char* __restrict__ wq,
                   float* __restrict__ sw) {
  const int row = blockIdx.x;           // s*N_DIM + d
  const int tid = threadIdx.x;
  const size_t base = (size_t)row * K_DIM + tid * 8;
  const float4 v0 = *(const float4*)(W + base);
  const float4 v1 = *(const float4*)(W + base + 4);
  float m = fmaxf(fmaxf(fmaxf(fabsf(v0.x), fabsf(v0.y)), fmaxf(fabsf(v0.z), fabsf(v0.w))),
                  fmaxf(fmaxf(fabsf(v1.x), fabsf(v1.y)), fmaxf(fabsf(v1.z), fabsf(v1.w))));
#pragma unroll
  for (int off = 1; off < 64; off <<= 1) m = fmaxf(m, __shfl_xor(m, off));
  __shared__ float rmx[4];
  if ((tid & 63) == 0) rmx[tid >> 6] = m;
  __syncthreads();
  const float rm = fmaxf(fmaxf(rmx[0], rmx[1]), fmaxf(rmx[2], rmx[3]));
  const float inv = 127.0f / fmaxf(rm, 1e-30f);
  const int q0 = __float2int_rn(v0.x * inv), q1 = __float2int_rn(v0.y * inv);
  const int q2 = __float2int_rn(v0.z * inv), q3 = __float2int_rn(v0.w * inv);
  const int q4 = __float2int_rn(v1.x * inv), q5 = __float2int_rn(v1.y * inv);
  const int q6 = __float2int_rn(v1.z * inv), q7 = __float2int_rn(v1.w * inv);
  const int lo = (q0 & 255) | ((q1 & 255) << 8) | ((q2 & 255) << 16) | ((q3 & 255) << 24);
  const int hi = (q4 & 255) | ((q5 & 255) << 8) | ((q6 & 255) << 16) | ((q7 & 255) << 24);
  ((int2*)wq)[(size_t)row * 256 + tid] = make_int2(lo, hi);
  if (tid == 0) sw[row] = rm * (1.0f / 127.0f);
}

// ------------- fused 4-segment GEMM, int8 MFMA 16x16x64 ---------------------
// Geometry as R10 (passing, conflicts=0): block 256 rows x 64 d x 4 segs,
// 8 waves 2Mx4N, per-wave 128 rows x 16 d x 4 segs; acc v4i[4][8].
// NEW vs R10: full-tile read BURST. All 12 ds_reads (4 B + 8 A) issue at
// tile start; the 8 MFMA phases then wait descending lgkmcnt(7..0) so read k
// has up to ~200cy of MFMA cover (> ~120cy LDS latency) and the LDS unit
// streams at throughput instead of the R10 trickle's per-phase ~100cy bubble.
// Staging/vmcnt identical to R10: A(t+1) both halves at tile start (VMEM,
// doesn't touch lgkmcnt), B(t+2) into dead 3rd buffer mid-tile, tail vmcnt(2),
// vmcnt(0) only at t==NT-2, 1 barrier/tile.
__global__ __launch_bounds__(512, 2)
void seg_gemm_kernel(const signed char* __restrict__ Xq,
                     const signed char* __restrict__ Wq,
                     const float* __restrict__ sx,
                     const float* __restrict__ sw,
                     const float* __restrict__ b_seg,
                     const float* __restrict__ thr,
                     const float* __restrict__ gates,
                     float* __restrict__ out) {
  extern __shared__ __align__(128) char smem[];   // 81920 bytes

  const int tid = threadIdx.x;
  const int lane = tid & 63;
  const int wid = tid >> 6;
  const int wm = wid >> 2;        // 0..1 (m half)
  const int wn = wid & 3;         // 0..3 (d quarter)

  // bijective XCD swizzle: 1024 blocks, 8 XCDs, 128 per XCD
  const int id = blockIdx.x;
  const int swz = (id & 7) * 128 + (id >> 3);
  const int m0 = (swz >> 5) * 256;
  const int n0 = (swz & 31) * 64;

  // ---- staging constants: dest L = tid*16 in an 8KB half; row = tid>>2,
  // slot = tid&3 holds global 16B-chunk kc = slot ^ ((row>>1)&3) ----
  const int row_st = tid >> 2;                       // 0..127
  const int kc    = (tid & 3) ^ ((tid >> 3) & 3);
  const int keOff = kc * 16;                         // byte==elem offset (i8)
  const int ldsd  = tid * 16;

  // ---- read constants: frag row = f*16+l15, chunk kg; slot = kg^((l15>>1)&3)
  const int l15 = lane & 15;
  const int kg  = lane >> 4;       // 0..3
  const int aSw = l15 * 64 + ((kg ^ ((l15 >> 1) & 3)) << 4);

  v4i acc[NSEG][8];
#pragma unroll
  for (int s = 0; s < NSEG; ++s)
#pragma unroll
    for (int f = 0; f < 8; ++f) acc[s][f] = (v4i){0, 0, 0, 0};

#define STAGE_A(t_, h_) do {                                                        \
    const signed char* s0_ = Xq + (size_t)(m0 + (h_) * 128 + row_st) * K_DIM + (t_) * 64 + keOff; \
    __builtin_amdgcn_global_load_lds((gas_ptr)s0_, (lds_ptr)(smem + ((t_) & 1) * 16384 + (h_) * 8192 + ldsd), 16, 0, 0); \
  } while (0)

#define STAGE_B(t_, h_, bb_) do {                                                   \
    const signed char* s0_ = Wq + ((size_t)((h_) * 2 + (tid >> 8)) * N_DIM + (n0 + ((tid >> 2) & 63))) * K_DIM + (t_) * 64 + keOff; \
    __builtin_amdgcn_global_load_lds((gas_ptr)s0_, (lds_ptr)(smem + 32768 + (bb_) * 16384 + (h_) * 8192 + ldsd), 16, 0, 0); \
  } while (0)

#define MFMAI(a_, b_, c_) __builtin_amdgcn_mfma_i32_16x16x64_i8(a_, b_, c_, 0, 0, 0)
#define LD16(p_) (*(const v4i*)(p_))
#define WAITL(n_) asm volatile("s_waitcnt lgkmcnt(" #n_ ")" ::: "memory")

#define MM4(f_) do {                                                                \
    __builtin_amdgcn_s_setprio(1);                                                  \
    acc[0][(f_)] = MFMAI(a[(f_)], bfr[0], acc[0][(f_)]);                            \
    acc[1][(f_)] = MFMAI(a[(f_)], bfr[1], acc[1][(f_)]);                            \
    acc[2][(f_)] = MFMAI(a[(f_)], bfr[2], acc[2][(f_)]);                            \
    acc[3][(f_)] = MFMAI(a[(f_)], bfr[3], acc[3][(f_)]);                            \
    __builtin_amdgcn_s_setprio(0);                                                  \
  } while (0)

  // ---- prologue: A(0) h0/h1, B(0) h0/h1, B(1) h0/h1; keep B(1) flying ----
  STAGE_A(0, 0); STAGE_A(0, 1);
  STAGE_B(0, 0, 0); STAGE_B(0, 1, 0);
  STAGE_B(1, 0, 1); STAGE_B(1, 1, 1);
  asm volatile("s_waitcnt vmcnt(2)" ::: "memory");   // A(0),B(0) landed
  __builtin_amdgcn_s_barrier();

  int bc = 0, bs = 2;   // current / stage-target B buffer (mod 3)
  for (int t = 0; t < NT; ++t) {
    const char* Ab = smem + (t & 1) * 16384 + wm * 8192;
    const char* Bb = smem + 32768 + bc * 16384;
    v4i bfr[NSEG];
    v4i a[8];

    // ---- full-tile burst: all 12 ds_reads out before any MFMA ----
    bfr[0] = LD16(Bb + 0 * 4096 + wn * 1024 + aSw);
    bfr[1] = LD16(Bb + 1 * 4096 + wn * 1024 + aSw);
    bfr[2] = LD16(Bb + 2 * 4096 + wn * 1024 + aSw);
    bfr[3] = LD16(Bb + 3 * 4096 + wn * 1024 + aSw);
    a[0] = LD16(Ab + 0 * 1024 + aSw);
    a[1] = LD16(Ab + 1 * 1024 + aSw);
    a[2] = LD16(Ab + 2 * 1024 + aSw);
    a[3] = LD16(Ab + 3 * 1024 + aSw);
    a[4] = LD16(Ab + 4 * 1024 + aSw);
    a[5] = LD16(Ab + 5 * 1024 + aSw);
    a[6] = LD16(Ab + 6 * 1024 + aSw);
    a[7] = LD16(Ab + 7 * 1024 + aSw);
    if (t + 1 < NT) { STAGE_A(t + 1, 0); STAGE_A(t + 1, 1); }   // VMEM only

    WAITL(7);  MM4(0);                               // bfr0-3 + a0 done
    WAITL(6);  MM4(1);
    WAITL(5);  MM4(2);
    WAITL(4);  MM4(3);
    WAITL(3);
    if (t + 2 < NT) STAGE_B(t + 2, 0, bs);
    MM4(4);
    WAITL(2);
    if (t + 2 < NT) STAGE_B(t + 2, 1, bs);
    MM4(5);
    WAITL(1);  MM4(6);
    WAITL(0);  MM4(7);

    if (t < NT - 2)      { asm volatile("s_waitcnt vmcnt(2)" ::: "memory"); }
    else if (t == NT - 2){ asm volatile("s_waitcnt vmcnt(0)" ::: "memory"); }
    __builtin_amdgcn_s_barrier();

    bc = (bc == 2) ? 0 : bc + 1;
    bs = (bs == 2) ? 0 : bs + 1;
  }
  asm volatile("s_waitcnt lgkmcnt(0) vmcnt(0)" ::: "memory");

  // ---------------- epilogue ----------------
  // C/D layout: col = lane&15 (d), row = (lane>>4)*4 + reg (dtype-independent)
  const int d = n0 + wn * 16 + l15;
  float bsv[NSEG], thv[NSEG], swv[NSEG];
#pragma unroll
  for (int s = 0; s < NSEG; ++s) {
    bsv[s] = b_seg[s * N_DIM + d];
    thv[s] = thr[s * N_DIM + d];
    swv[s] = sw[s * N_DIM + d];
  }
#pragma unroll
  for (int f = 0; f < 8; ++f) {
#pragma unroll
    for (int r = 0; r < 4; ++r) {
      const int brow = m0 + wm * 128 + f * 16 + kg * 4 + r;
      const float sxr = sx[brow];
      const float4 g = *(const float4*)(gates + (size_t)brow * 4);
      const float gv[NSEG] = {g.x, g.y, g.z, g.w};
      float sum = 0.f, prod = 1.f;
#pragma unroll
      for (int s = 0; s < NSEG; ++s) {
        const float seg = (float)acc[s][f][r] * (sxr * swv[s]) + bsv[s];
        const float pl = 1.f / (1.f + __expf(-5.f * (seg - thv[s])));
        const float st = seg * pl * gv[s];
        sum += st;
        prod *= st;
      }
      const float gm = sqrtf(sqrtf(fabsf(prod)));   // |prod|^(1/4)
      out[(size_t)brow * N_DIM + d] = sum + 0.1f * (prod < 0.f ? -gm : gm);
    }
  }
#undef STAGE_A
#undef STAGE_B
#undef MFMAI
#undef LD16
#undef WAITL
#undef MM4
}

extern "C" void kernel_launch(void* const* d_in, const int* in_sizes, int n_in,
                              void* d_out, int out_size, void* d_ws, size_t ws_size,
                              hipStream_t stream) {
  const float* x      = (const float*)d_in[0];
  const float* W_seg  = (const float*)d_in[1];
  const float* b_seg  = (const float*)d_in[2];
  const float* thr    = (const float*)d_in[3];
  const float* W_gate = (const float*)d_in[4];
  const float* b_gate = (const float*)d_in[5];
  float* out = (float*)d_out;

  // workspace: xq 16MB | wq 32MB | sx 32KB | sw 32KB | gates 128KB
  signed char* xq = (signed char*)d_ws;
  signed char* wq = xq + (size_t)B_DIM * K_DIM;
  float* sx = (float*)(wq + (size_t)NSEG * N_DIM * K_DIM);
  float* sw = sx + B_DIM;
  float* gates = sw + NSEG * N_DIM;

  xquant_gates_kernel<<<B_DIM, 256, 0, stream>>>(x, W_gate, b_gate, xq, sx, gates);
  wquant_kernel<<<NSEG * N_DIM, 256, 0, stream>>>(W_seg, wq, sw);

  hipFuncSetAttribute((const void*)seg_gemm_kernel,
                      hipFuncAttributeMaxDynamicSharedMemorySize, 81920);
  seg_gemm_kernel<<<1024, 512, 81920, stream>>>(xq, wq, sx, sw, b_seg, thr, gates, out);
}